// Round 10
// baseline (2841.620 us; speedup 1.0000x reference)
//
#include <hip/hip_runtime.h>

typedef __attribute__((ext_vector_type(8))) short short8;
typedef __attribute__((ext_vector_type(4))) float f32x4;

#define DEVINL __device__ __forceinline__

DEVINL unsigned short f2bf(float f) {
  unsigned int u = __builtin_bit_cast(unsigned int, f);
  unsigned int r = u + 0x7FFFu + ((u >> 16) & 1u);  // RNE
  return (unsigned short)(r >> 16);
}
DEVINL float bf2f(unsigned short u) {
  unsigned int x = ((unsigned int)u) << 16;
  return __builtin_bit_cast(float, x);
}
DEVINL float sig_(float x) { return 1.f / (1.f + __expf(-x)); }
DEVINL float tanh_(float x) { return 2.f / (1.f + __expf(-2.f * x)) - 1.f; }

DEVINL void gld16(void* lds, const void* g) {
  __builtin_amdgcn_global_load_lds(
      (const __attribute__((address_space(1))) unsigned int*)g,
      (__attribute__((address_space(3))) unsigned int*)lds, 16, 0, 0);
}

// ---- coherent 8B store: agent-scope relaxed atomic writes through to the
// coherence point, so cross-XCD readers that L2-miss see fresh data. ----
DEVINL void coh_st(unsigned long long* p, unsigned long long v) {
  __hip_atomic_store(p, v, __ATOMIC_RELAXED, __HIP_MEMORY_SCOPE_AGENT);
}

// pack 4 16-bit lane values (lanes L, L^s0, L^s1, L^(s0|s1)) into one u64
DEVINL unsigned long long pack4w(unsigned int u, int lane, int s0, int s1) {
  unsigned int p1 = (unsigned int)__shfl_xor((int)u, s0);
  unsigned int lo2 = (lane & s0) ? ((p1 & 0xFFFFu) | (u << 16))
                                 : ((u & 0xFFFFu) | (p1 << 16));
  unsigned int p2 = (unsigned int)__shfl_xor((int)lo2, s1);
  unsigned int lo = (lane & s1) ? p2 : lo2;
  unsigned int hi = (lane & s1) ? lo2 : p2;
  return ((unsigned long long)hi << 32) | lo;
}

// ---- split-phase generation barrier helpers ----
DEVINL void block_arrive(int* cnt, int* flag, int target, int gen) {
  if (threadIdx.x == 0) {
    if (__hip_atomic_fetch_add(cnt, 1, __ATOMIC_RELAXED, __HIP_MEMORY_SCOPE_AGENT) == target)
      __hip_atomic_store(flag, gen, __ATOMIC_RELAXED, __HIP_MEMORY_SCOPE_AGENT);
  }
}
DEVINL void wave_poll(const int* flag, int t) {
  int done = 0;
  while (!done) {
    int fl = 0;
    if ((threadIdx.x & 63) == 0)
      fl = (__hip_atomic_load(flag, __ATOMIC_RELAXED, __HIP_MEMORY_SCOPE_AGENT) > t) ? 1 : 0;
    done = __shfl(fl, 0);
    if (!done) __builtin_amdgcn_s_sleep(1);
  }
  __builtin_amdgcn_sched_barrier(0);  // keep following loads below the poll
  asm volatile("" ::: "memory");
}

// helper-work argument bundle (single by-value kernel arg; zero => inactive)
struct SetupArgs {
  const float* s0; unsigned short* d0;  // enc Wih L1   (f32x4 count 1048576)
  const float* s1; unsigned short* d1;  // enc Whh L1   (524288)
  const float* s2; unsigned short* d2;  // dec Wih0     (2097152)
  const float* s3; unsigned short* d3;  // dec Wih1     (1048576)
  const float* s4; unsigned short* d4;  // dec Whh0     (1048576)
  const float* s5; unsigned short* d5;  // dec Whh1     (1048576)
  const float* s6; unsigned short* d6;  // W_out        (8192000)
  const float* ba; const float* bb; float* bd;  // dec bias (2048 groups)
  const int* y; const float* emb; unsigned short* inp0;  // tgt embed
};

// ---------------------------------------------------------------------------
// bf16 GEMM: C[M,N] = A[M,K] @ Bt[N,K]^T + bias[N].  BK=64, 32 MFMA/iter.
// mode 0: f32 C. mode 1: logits scatter f32. mode 2: bf16 C.
// ---------------------------------------------------------------------------
__global__ __launch_bounds__(256) void gemm_bf16(
    const unsigned short* __restrict__ A, const unsigned short* __restrict__ Bt,
    void* __restrict__ C, const float* __restrict__ bias,
    int K, int N, int Mvalid, int mode) {
  __shared__ unsigned short lA[1024 * 8];
  __shared__ unsigned short lB[1024 * 8];
  const int tid = threadIdx.x;
  const int lane = tid & 63, wid = tid >> 6;
  const int wm = wid >> 1, wn = wid & 1;
  const int bn = blockIdx.x, bm = blockIdx.y;
  const size_t K_ = (size_t)K;

  const unsigned short* gAc[4];
  const unsigned short* gBc[4];
  unsigned short* lAc[4];
  unsigned short* lBc[4];
#pragma unroll
  for (int c = 0; c < 4; c++) {
    const int s = c * 256 + tid;
    const int r = s & 127, kb = s >> 7;  // kb 0..7 (k-chunk of 8)
    gAc[c] = A + (size_t)(bm * 128 + r) * K_ + kb * 8;
    gBc[c] = Bt + (size_t)(bn * 128 + r) * K_ + kb * 8;
    lAc[c] = lA + (size_t)(c * 256 + wid * 64) * 8;
    lBc[c] = lB + (size_t)(c * 256 + wid * 64) * 8;
  }

  f32x4 acc[4][4] = {};
  const int kg = lane >> 4, lr = lane & 15;

  for (int kt = 0; kt < K; kt += 64) {
#pragma unroll
    for (int c = 0; c < 4; c++) {
      gld16(lAc[c], gAc[c] + kt);
      gld16(lBc[c], gBc[c] + kt);
    }
    __syncthreads();
#pragma unroll
    for (int ks = 0; ks < 2; ks++) {
      const int kgi = ks * 4 + kg;
      short8 af[4], bfr[4];
#pragma unroll
      for (int fm = 0; fm < 4; fm++)
        af[fm] = *(const short8*)&lA[(size_t)(kgi * 128 + wm * 64 + fm * 16 + lr) * 8];
#pragma unroll
      for (int fn = 0; fn < 4; fn++)
        bfr[fn] = *(const short8*)&lB[(size_t)(kgi * 128 + wn * 64 + fn * 16 + lr) * 8];
#pragma unroll
      for (int fm = 0; fm < 4; fm++)
#pragma unroll
        for (int fn = 0; fn < 4; fn++)
          acc[fm][fn] =
              __builtin_amdgcn_mfma_f32_16x16x32_bf16(af[fm], bfr[fn], acc[fm][fn], 0, 0, 0);
    }
    __syncthreads();
  }

#pragma unroll
  for (int fn = 0; fn < 4; fn++) {
    const int col = bn * 128 + wn * 64 + fn * 16 + lr;
    const float bv = bias ? bias[col] : 0.f;
#pragma unroll
    for (int fm = 0; fm < 4; fm++) {
      const int row0 = bm * 128 + wm * 64 + fm * 16 + kg * 4;
#pragma unroll
      for (int r = 0; r < 4; r++) {
        const int m = row0 + r;
        if (m < Mvalid) {
          const float v = acc[fm][fn][r] + bv;
          if (mode == 0) {
            ((float*)C)[(size_t)m * N + col] = v;
          } else if (mode == 1) {
            const int b = m & 31, t = m >> 5;
            ((float*)C)[(size_t)b * 2016000 + (size_t)t * 32000 + col] = v;
          } else {
            ((unsigned short*)C)[(size_t)m * N + col] = f2bf(v);
          }
        }
      }
    }
  }
}

// ---------------------------------------------------------------------------
// Encoder chain + fused setup helpers.
// Blocks 0..31: chain (dir*16 + jtile32), 128KB dyn LDS, Henc[t][dir][32][512]
// fresh-address timeline. Blocks 32..255 (L0 launch only): grid-stride setup
// work (weight converts, dec bias, tgt embedding) on otherwise-idle CUs.
// ---------------------------------------------------------------------------
__global__ __launch_bounds__(128, 1) void enc_chain(
    const unsigned short* __restrict__ Whh, const unsigned short* __restrict__ G,
    unsigned short* __restrict__ Henc, unsigned short* __restrict__ seq_out,
    float* __restrict__ c_out, int* bar, SetupArgs sa) {
  const int bid = (int)blockIdx.x;
  if (bid >= 32) {
    // ---------------- helper blocks: fused setup ----------------
    const long n1 = 1048576, n2 = 524288, n3 = 2097152, n4 = 1048576;
    const long n5 = 1048576, n6 = 1048576, n7 = 8192000, nb = 2048, ne = 524288;
    const long e1 = n1, e2 = e1 + n2, e3 = e2 + n3, e4 = e3 + n4;
    const long e5 = e4 + n5, e6 = e5 + n6, e7 = e6 + n7, e8 = e7 + nb, e9 = e8 + ne;
    const long stride = 224l * 128;
    for (long i = (long)(bid - 32) * 128 + threadIdx.x; i < e9; i += stride) {
      if (i < e7) {
        const float* s;
        unsigned short* d;
        long k;
        if (i < e1) { s = sa.s0; d = sa.d0; k = i; }
        else if (i < e2) { s = sa.s1; d = sa.d1; k = i - e1; }
        else if (i < e3) { s = sa.s2; d = sa.d2; k = i - e2; }
        else if (i < e4) { s = sa.s3; d = sa.d3; k = i - e3; }
        else if (i < e5) { s = sa.s4; d = sa.d4; k = i - e4; }
        else if (i < e6) { s = sa.s5; d = sa.d5; k = i - e5; }
        else { s = sa.s6; d = sa.d6; k = i - e6; }
        f32x4 v = *(const f32x4*)&s[k * 4];
        ushort4 o = {f2bf(v.x), f2bf(v.y), f2bf(v.z), f2bf(v.w)};
        *(ushort4*)&d[k * 4] = o;
      } else if (i < e8) {
        const long k = i - e7;
        f32x4 a = *(const f32x4*)&sa.ba[k * 4];
        f32x4 b = *(const f32x4*)&sa.bb[k * 4];
        f32x4 o = {a.x + b.x, a.y + b.y, a.z + b.z, a.w + b.w};
        *(f32x4*)&sa.bd[k * 4] = o;
      } else {
        const long k = i - e8;
        const int row = (int)(k >> 8), col = (int)(k & 255) * 4;
        if (row < 2016) {
          const int t = row >> 5, b = row & 31;
          const int tok = sa.y[b * 64 + t];
          f32x4 v = *(const f32x4*)(sa.emb + (size_t)tok * 1024 + col);
          ushort4 o = {f2bf(v.x), f2bf(v.y), f2bf(v.z), f2bf(v.w)};
          *(ushort4*)&sa.inp0[(size_t)row * 2048 + col] = o;
        } else {
          ushort4 z = {0, 0, 0, 0};
          *(ushort4*)&sa.inp0[(size_t)row * 2048 + col] = z;
          *(ushort4*)&sa.inp0[(size_t)row * 2048 + 1024 + col] = z;
        }
      }
    }
    return;
  }
  // ---------------- chain blocks ----------------
  extern __shared__ unsigned short lw[];
  const int tid = threadIdx.x, lane = tid & 63, w = tid >> 6;
  const int lr = lane & 15, kg = lane >> 4;
  const int dir = bid >> 4, j0 = (bid & 15) * 32;
  int* cnt = bar + dir * 32;
  int* flag = cnt + 16;
  const unsigned short* Wd = Whh + (size_t)dir * 2048 * 512;
  for (int it = 0; it < 64; it++) {
    const int idx = (it * 128 + tid) * 16;
    const int r = idx >> 10, o = idx & 1023;
    const unsigned short* src = Wd + (size_t)((r >> 5) * 512 + j0 + (r & 31)) * 512 + (o >> 1);
    *(short8*)((char*)lw + r * 1024 + (o ^ ((r & 7) << 4))) = *(const short8*)src;
  }
  float cc[2][4] = {};
  float gpre[4][2][4];
  auto fetch_g = [&](int t) {
    const int s_idx = dir ? (63 - t) : t;
#pragma unroll
    for (int r = 0; r < 4; r++) {
      const unsigned short* Gr =
          G + (size_t)(s_idx * 32 + (w * 16 + kg * 4 + r)) * 4096 + dir * 2048;
#pragma unroll
      for (int jh = 0; jh < 2; jh++) {
        const int jj = j0 + jh * 16 + lr;
        gpre[r][jh][0] = bf2f(Gr[jj]);
        gpre[r][jh][1] = bf2f(Gr[512 + jj]);
        gpre[r][jh][2] = bf2f(Gr[1024 + jj]);
        gpre[r][jh][3] = bf2f(Gr[1536 + jj]);
      }
    }
  };
  fetch_g(0);
  __syncthreads();
  for (int t = 0; t < 64; t++) {
    const unsigned short* hA =
        Henc + ((size_t)(t * 2 + dir) * 32 + w * 16 + lr) * 512 + kg * 8;
    short8 areg[16];
#pragma unroll
    for (int kc = 0; kc < 16; kc++) areg[kc] = *(const short8*)(hA + kc * 32);
    f32x4 acc[8] = {};
#pragma unroll
    for (int kc = 0; kc < 16; kc++)
#pragma unroll
      for (int nt = 0; nt < 8; nt++) {
        const int rr = nt * 16 + lr;
        short8 bf = *(const short8*)((const char*)lw + rr * 1024 +
                                     ((kc * 64 + kg * 16) ^ ((rr & 7) << 4)));
        acc[nt] = __builtin_amdgcn_mfma_f32_16x16x32_bf16(areg[kc], bf, acc[nt], 0, 0, 0);
      }
    const int s_idx = dir ? (63 - t) : t;
    unsigned long long* HWU =
        (unsigned long long*)Henc + ((size_t)((t + 1) * 2 + dir) * 32) * 128;
#pragma unroll
    for (int r = 0; r < 4; r++) {
      const int b = w * 16 + kg * 4 + r;
#pragma unroll
      for (int jh = 0; jh < 2; jh++) {
        const float gi = gpre[r][jh][0] + acc[jh + 0][r];
        const float gf = gpre[r][jh][1] + acc[jh + 2][r];
        const float gg = gpre[r][jh][2] + acc[jh + 4][r];
        const float go = gpre[r][jh][3] + acc[jh + 6][r];
        const float cn = sig_(gf) * cc[jh][r] + sig_(gi) * tanh_(gg);
        const float hn = sig_(go) * tanh_(cn);
        cc[jh][r] = cn;
        unsigned long long pk = pack4w((unsigned int)f2bf(hn), lane, 1, 2);
        if ((lane & 3) == 0) {
          const int jjb = j0 + jh * 16 + lr;  // lr multiple of 4 here
          coh_st(HWU + b * 128 + (jjb >> 2), pk);
          if (seq_out)
            *(unsigned long long*)&seq_out[(size_t)(s_idx * 32 + b) * 1024 + dir * 512 +
                                           jjb] = pk;
        }
      }
    }
    if (t < 63) {
      __syncthreads();  // drains h stores (vmcnt) before arrive
      block_arrive(cnt, flag, t * 16 + 15, t + 1);
      fetch_g(t + 1);  // overlap G prefetch with barrier wait
      wave_poll(flag, t);
    }
  }
#pragma unroll
  for (int r = 0; r < 4; r++)
#pragma unroll
    for (int jh = 0; jh < 2; jh++)
      c_out[(dir * 32 + (w * 16 + kg * 4 + r)) * 512 + j0 + jh * 16 + lr] = cc[jh][r];
}

// ---------------------------------------------------------------------------
// Decoder chain (per cell; K=1024 recurrent half): grid 64 (jtile16),
// block 128, 128KB dyn LDS. Hext rows (t+1)*32+b; rows 0..31 = init state.
// ---------------------------------------------------------------------------
__global__ __launch_bounds__(128, 1) void dec_chain(
    const unsigned short* __restrict__ W, const unsigned short* __restrict__ G,
    const float* __restrict__ cinit, unsigned short* __restrict__ Hext,
    int* bar) {
  extern __shared__ unsigned short lw[];
  const int tid = threadIdx.x, lane = tid & 63, w = tid >> 6;
  const int lr = lane & 15, kg = lane >> 4;
  const int j0 = (int)blockIdx.x * 16, j = j0 + lr;
  int* cnt = bar;
  int* flag = bar + 16;
  for (int it = 0; it < 64; it++) {
    const int idx = (it * 128 + tid) * 16;
    const int r = idx >> 11, o = idx & 2047;
    const unsigned short* src = W + (size_t)((r >> 4) * 1024 + j0 + (r & 15)) * 1024 + (o >> 1);
    *(short8*)((char*)lw + r * 2048 + (o ^ ((r & 7) << 4))) = *(const short8*)src;
  }
  float cc[4];
#pragma unroll
  for (int r = 0; r < 4; r++) cc[r] = cinit[(w * 16 + kg * 4 + r) * 1024 + j];
  float gpre[4][4];
  auto fetch_g = [&](int k) {
#pragma unroll
    for (int r = 0; r < 4; r++) {
      const unsigned short* Gr = G + (size_t)(k * 32 + (w * 16 + kg * 4 + r)) * 4096 + j;
      gpre[r][0] = bf2f(Gr[0]);
      gpre[r][1] = bf2f(Gr[1024]);
      gpre[r][2] = bf2f(Gr[2048]);
      gpre[r][3] = bf2f(Gr[3072]);
    }
  };
  fetch_g(0);
  __syncthreads();
  for (int k = 0; k < 63; k++) {
    const unsigned short* hA = Hext + ((size_t)k * 32 + w * 16 + lr) * 1024 + kg * 8;
    short8 areg[32];
#pragma unroll
    for (int kc = 0; kc < 32; kc++) areg[kc] = *(const short8*)(hA + kc * 32);
    f32x4 acc[4] = {};
#pragma unroll
    for (int kc = 0; kc < 32; kc++)
#pragma unroll
      for (int g = 0; g < 4; g++) {
        const int rr = g * 16 + lr;
        short8 bf = *(const short8*)((const char*)lw + rr * 2048 +
                                     ((kc * 64 + kg * 16) ^ ((rr & 7) << 4)));
        acc[g] = __builtin_amdgcn_mfma_f32_16x16x32_bf16(areg[kc], bf, acc[g], 0, 0, 0);
      }
    unsigned long long* HWU = (unsigned long long*)Hext + ((size_t)(k + 1) * 32) * 256;
#pragma unroll
    for (int r = 0; r < 4; r++) {
      const int b = w * 16 + kg * 4 + r;
      const float gi = gpre[r][0] + acc[0][r];
      const float gf = gpre[r][1] + acc[1][r];
      const float gg = gpre[r][2] + acc[2][r];
      const float go = gpre[r][3] + acc[3][r];
      const float cn = sig_(gf) * cc[r] + sig_(gi) * tanh_(gg);
      const float hn = sig_(go) * tanh_(cn);
      cc[r] = cn;
      unsigned long long pk = pack4w((unsigned int)f2bf(hn), lane, 1, 2);
      if ((lane & 3) == 0)
        coh_st(HWU + b * 256 + ((j0 + lr) >> 2), pk);
    }
    if (k < 62) {
      __syncthreads();  // drain h stores before arrive
      block_arrive(cnt, flag, k * 64 + 63, k + 1);
      fetch_g(k + 1);  // overlap G prefetch with barrier wait
      wave_poll(flag, k);
    }
  }
}

// ---------------------------------------------------------------------------
// Setup kernels (pre-chain only)
// ---------------------------------------------------------------------------
__global__ void cvt_bf16(const float* __restrict__ in, unsigned short* __restrict__ out,
                         long n4) {
  long i = (long)blockIdx.x * blockDim.x + threadIdx.x;
  const long stride = (long)gridDim.x * blockDim.x;
  for (; i < n4; i += stride) {
    f32x4 v = *(const f32x4*)&in[i * 4];
    ushort4 o = {f2bf(v.x), f2bf(v.y), f2bf(v.z), f2bf(v.w)};
    *(ushort4*)&out[i * 4] = o;
  }
}

__global__ void bias_comb(const float* __restrict__ a, const float* __restrict__ b,
                          float* __restrict__ out, int n) {
  int i = blockIdx.x * blockDim.x + threadIdx.x;
  if (i < n) out[i] = a[i] + b[i];
}

__global__ void embed_src(const int* __restrict__ x, const float* __restrict__ emb,
                          unsigned short* __restrict__ A0) {
  const int row = blockIdx.x;
  const int s = row >> 5, b = row & 31;
  const int tok = x[b * 64 + (63 - s)];
  const int col = threadIdx.x * 4;
  f32x4 v = *(const f32x4*)(emb + (size_t)tok * 1024 + col);
  ushort4 o = {f2bf(v.x), f2bf(v.y), f2bf(v.z), f2bf(v.w)};
  *(ushort4*)&A0[(size_t)row * 1024 + col] = o;
}

__global__ void fill_ctx2(const unsigned short* __restrict__ Hl1,
                          unsigned short* __restrict__ inp0) {
  const int row = blockIdx.x;
  const int b = row & 31;
  const int col = threadIdx.x * 4;
  const int dir = col >> 9, jj = col & 511;
  ushort4 v = *(const ushort4*)(Hl1 + ((size_t)dir * 32 + b) * 512 + jj);
  *(ushort4*)&inp0[(size_t)row * 2048 + 1024 + col] = v;
}

// init rows 0..31 of H0ext/H1ext + c bufs from encoder finals; grid 128 x 256
__global__ void dec_init2(const unsigned short* __restrict__ Hl0,
                          const unsigned short* __restrict__ Hl1,
                          const float* __restrict__ Cl0, const float* __restrict__ Cl1,
                          unsigned short* __restrict__ H0e, unsigned short* __restrict__ H1e,
                          float* __restrict__ c0, float* __restrict__ c1) {
  const int i = blockIdx.x * 256 + threadIdx.x;
  const int b = i >> 10, col = i & 1023;
  const int dir = col >> 9, jj = col & 511;
  const int se = (dir * 32 + b) * 512 + jj;
  const int de = b * 1024 + col;
  H0e[de] = Hl0[se];
  H1e[de] = Hl1[se];
  c0[de] = Cl0[se];
  c1[de] = Cl1[se];
}

// ---------------------------------------------------------------------------
extern "C" void kernel_launch(void* const* d_in, const int* in_sizes, int n_in,
                              void* d_out, int out_size, void* d_ws, size_t ws_size,
                              hipStream_t stream) {
  const int* x = (const int*)d_in[0];
  const int* y = (const int*)d_in[1];
  const float* src_emb = (const float*)d_in[2];
  const float* tgt_emb = (const float*)d_in[3];
  const float* enc_W_ih = (const float*)d_in[4];
  const float* enc_W_hh = (const float*)d_in[5];
  const float* enc_b_ih = (const float*)d_in[6];
  const float* enc_b_hh = (const float*)d_in[7];
  const float* dec_W_ih0 = (const float*)d_in[8];
  const float* dec_W_ih1 = (const float*)d_in[9];
  const float* dec_W_hh = (const float*)d_in[10];
  const float* dec_b_ih = (const float*)d_in[11];
  const float* dec_b_hh = (const float*)d_in[12];
  const float* W_out = (const float*)d_in[13];
  const float* b_out = (const float*)d_in[14];
  float* out = (float*)d_out;

  char* ws = (char*)d_ws;
  size_t off = 0;
  auto alloc = [&](size_t bytes) -> void* {
    void* p = ws + off;
    off += (bytes + 255) & ~(size_t)255;
    return p;
  };
  unsigned short* A0 = (unsigned short*)alloc(2048ull * 1024 * 2);
  unsigned short* seq1 = (unsigned short*)alloc(2048ull * 1024 * 2);
  unsigned short* Wih_bf = (unsigned short*)alloc(2ull * 4096 * 1024 * 2);
  unsigned short* Wih0_bf = (unsigned short*)alloc(4096ull * 2048 * 2);
  unsigned short* Wih1_bf = (unsigned short*)alloc(4096ull * 1024 * 2);
  unsigned short* Wout_bf = (unsigned short*)alloc(32000ull * 1024 * 2);
  unsigned short* G = (unsigned short*)alloc(2048ull * 4096 * 2);  // bf16 gates (reused)
  unsigned short* inp0 = (unsigned short*)alloc(2048ull * 2048 * 2);
  unsigned short* Whh_enc_bf = (unsigned short*)alloc(2ull * 2 * 2048 * 512 * 2);
  unsigned short* Whh0_bf = (unsigned short*)alloc(4096ull * 1024 * 2);
  unsigned short* Whh1_bf = (unsigned short*)alloc(4096ull * 1024 * 2);
  unsigned short* H0ext = (unsigned short*)alloc(2080ull * 1024 * 2);  // row0-31=init
  unsigned short* H1ext = (unsigned short*)alloc(2080ull * 1024 * 2);
  unsigned short* Henc0 = (unsigned short*)alloc(65ull * 2 * 32 * 512 * 2);  // [t][d][b][j]
  unsigned short* Henc1 = (unsigned short*)alloc(65ull * 2 * 32 * 512 * 2);
  float* encbias = (float*)alloc(2ull * 4096 * 4);
  float* decdb = (float*)alloc(2ull * 4096 * 4);
  float* c_l0 = (float*)alloc(2ull * 32 * 512 * 4);
  float* c_l1 = (float*)alloc(2ull * 32 * 512 * 4);
  float* c0buf = (float*)alloc(32ull * 1024 * 4);
  float* c1buf = (float*)alloc(32ull * 1024 * 4);
  int* bar = (int*)alloc(1024 * 4);  // gen-barrier pairs (stride 32 ints)
  if (off > ws_size) return;

  (void)hipFuncSetAttribute((const void*)enc_chain,
                            hipFuncAttributeMaxDynamicSharedMemorySize, 131072);
  (void)hipFuncSetAttribute((const void*)dec_chain,
                            hipFuncAttributeMaxDynamicSharedMemorySize, 131072);

  // ---- minimal pre-chain setup (only what L0 GEMM + chain L0 need) ----
  cvt_bf16<<<256, 256, 0, stream>>>(enc_W_ih, Wih_bf, 1048576);          // layer 0
  cvt_bf16<<<256, 256, 0, stream>>>(enc_W_hh, Whh_enc_bf, 524288);       // layer 0
  bias_comb<<<32, 256, 0, stream>>>(enc_b_ih, enc_b_hh, encbias, 8192);  // both layers
  embed_src<<<2048, 256, 0, stream>>>(x, src_emb, A0);
  hipMemsetAsync(Henc0, 0, 2ull * 32 * 512 * 2, stream);  // t=0 slice
  hipMemsetAsync(Henc1, 0, 2ull * 32 * 512 * 2, stream);  // t=0 slice
  hipMemsetAsync(bar, 0, 1024 * 4, stream);               // replay-safe barrier reset

  // ---- encoder layer 0 (chain blocks 0..31; helpers 32..255 do the rest of
  //      the weight converts / dec bias / tgt embedding concurrently) ----
  gemm_bf16<<<dim3(32, 16), 256, 0, stream>>>(A0, Wih_bf, G, encbias, 1024, 4096, 2048, 2);
  SetupArgs sa;
  sa.s0 = enc_W_ih + 4096ll * 1024;    sa.d0 = Wih_bf + 4096ull * 1024;
  sa.s1 = enc_W_hh + 2ll * 2048 * 512; sa.d1 = Whh_enc_bf + 2ull * 2048 * 512;
  sa.s2 = dec_W_ih0;                   sa.d2 = Wih0_bf;
  sa.s3 = dec_W_ih1;                   sa.d3 = Wih1_bf;
  sa.s4 = dec_W_hh;                    sa.d4 = Whh0_bf;
  sa.s5 = dec_W_hh + 4096ll * 1024;    sa.d5 = Whh1_bf;
  sa.s6 = W_out;                       sa.d6 = Wout_bf;
  sa.ba = dec_b_ih; sa.bb = dec_b_hh;  sa.bd = decdb;
  sa.y = y; sa.emb = tgt_emb; sa.inp0 = inp0;
  enc_chain<<<256, 128, 131072, stream>>>(Whh_enc_bf, G, Henc0, seq1, c_l0, bar + 0, sa);

  // ---- encoder layer 1 ----
  gemm_bf16<<<dim3(32, 16), 256, 0, stream>>>(seq1, Wih_bf + 4096ull * 1024, G,
                                              encbias + 4096, 1024, 4096, 2048, 2);
  SetupArgs sz = {};
  enc_chain<<<32, 128, 131072, stream>>>(Whh_enc_bf + 2ull * 2048 * 512, G, Henc1, nullptr,
                                         c_l1, bar + 128, sz);

  // ---- decoder setup ----
  dec_init2<<<128, 256, 0, stream>>>(Henc0 + 64ull * 2 * 32 * 512,
                                     Henc1 + 64ull * 2 * 32 * 512, c_l0, c_l1,
                                     H0ext, H1ext, c0buf, c1buf);
  fill_ctx2<<<2016, 256, 0, stream>>>(Henc1 + 64ull * 2 * 32 * 512, inp0);
  gemm_bf16<<<dim3(32, 16), 256, 0, stream>>>(inp0, Wih0_bf, G, decdb, 2048, 4096, 2048, 2);

  // ---- decoder cell0 chain ----
  dec_chain<<<64, 128, 131072, stream>>>(Whh0_bf, G, c0buf, H0ext, bar + 256);
  // ---- G1 = H0seq @ Wih1^T + db1 ----
  gemm_bf16<<<dim3(32, 16), 256, 0, stream>>>(H0ext + 32ull * 1024, Wih1_bf, G,
                                              decdb + 4096, 1024, 4096, 2016, 2);
  // ---- decoder cell1 chain ----
  dec_chain<<<64, 128, 131072, stream>>>(Whh1_bf, G, c1buf, H1ext, bar + 384);

  // ---- logits ----
  gemm_bf16<<<dim3(250, 16), 256, 0, stream>>>(H1ext + 32ull * 1024, Wout_bf, out, b_out,
                                               1024, 32000, 2016, 1);
}

// Round 11
// 2510.398 us; speedup vs baseline: 1.1319x; 1.1319x over previous
//
#include <hip/hip_runtime.h>

typedef __attribute__((ext_vector_type(8))) short short8;
typedef __attribute__((ext_vector_type(4))) float f32x4;

#define DEVINL __device__ __forceinline__

DEVINL unsigned short f2bf(float f) {
  unsigned int u = __builtin_bit_cast(unsigned int, f);
  unsigned int r = u + 0x7FFFu + ((u >> 16) & 1u);  // RNE
  return (unsigned short)(r >> 16);
}
DEVINL float bf2f(unsigned short u) {
  unsigned int x = ((unsigned int)u) << 16;
  return __builtin_bit_cast(float, x);
}
DEVINL float sig_(float x) { return 1.f / (1.f + __expf(-x)); }
DEVINL float tanh_(float x) { return 2.f / (1.f + __expf(-2.f * x)) - 1.f; }

DEVINL void gld16(void* lds, const void* g) {
  __builtin_amdgcn_global_load_lds(
      (const __attribute__((address_space(1))) unsigned int*)g,
      (__attribute__((address_space(3))) unsigned int*)lds, 16, 0, 0);
}

// ---- coherent 8B store: agent-scope relaxed atomic writes through to the
// coherence point, so cross-XCD readers that L2-miss see fresh data. ----
DEVINL void coh_st(unsigned long long* p, unsigned long long v) {
  __hip_atomic_store(p, v, __ATOMIC_RELAXED, __HIP_MEMORY_SCOPE_AGENT);
}

// pack 4 16-bit lane values (lanes L, L^s0, L^s1, L^(s0|s1)) into one u64
DEVINL unsigned long long pack4w(unsigned int u, int lane, int s0, int s1) {
  unsigned int p1 = (unsigned int)__shfl_xor((int)u, s0);
  unsigned int lo2 = (lane & s0) ? ((p1 & 0xFFFFu) | (u << 16))
                                 : ((u & 0xFFFFu) | (p1 << 16));
  unsigned int p2 = (unsigned int)__shfl_xor((int)lo2, s1);
  unsigned int lo = (lane & s1) ? p2 : lo2;
  unsigned int hi = (lane & s1) ? lo2 : p2;
  return ((unsigned long long)hi << 32) | lo;
}

// ---- split-phase generation barrier helpers ----
DEVINL void block_arrive(int* cnt, int* flag, int target, int gen) {
  if (threadIdx.x == 0) {
    if (__hip_atomic_fetch_add(cnt, 1, __ATOMIC_RELAXED, __HIP_MEMORY_SCOPE_AGENT) == target)
      __hip_atomic_store(flag, gen, __ATOMIC_RELAXED, __HIP_MEMORY_SCOPE_AGENT);
  }
}
DEVINL void wave_poll(const int* flag, int t) {
  int done = 0;
  while (!done) {
    int fl = 0;
    if ((threadIdx.x & 63) == 0)
      fl = (__hip_atomic_load(flag, __ATOMIC_RELAXED, __HIP_MEMORY_SCOPE_AGENT) > t) ? 1 : 0;
    done = __shfl(fl, 0);
    if (!done) __builtin_amdgcn_s_sleep(1);
  }
  __builtin_amdgcn_sched_barrier(0);  // keep following loads below the poll
  asm volatile("" ::: "memory");
}

// ---------------------------------------------------------------------------
// bf16 GEMM: C[M,N] = A[M,K] @ Bt[N,K]^T + bias[N].  BK=64, 32 MFMA/iter.
// mode 0: f32 C. mode 1: logits scatter f32. mode 2: bf16 C.
// ---------------------------------------------------------------------------
__global__ __launch_bounds__(256) void gemm_bf16(
    const unsigned short* __restrict__ A, const unsigned short* __restrict__ Bt,
    void* __restrict__ C, const float* __restrict__ bias,
    int K, int N, int Mvalid, int mode) {
  __shared__ unsigned short lA[1024 * 8];
  __shared__ unsigned short lB[1024 * 8];
  const int tid = threadIdx.x;
  const int lane = tid & 63, wid = tid >> 6;
  const int wm = wid >> 1, wn = wid & 1;
  const int bn = blockIdx.x, bm = blockIdx.y;
  const size_t K_ = (size_t)K;

  const unsigned short* gAc[4];
  const unsigned short* gBc[4];
  unsigned short* lAc[4];
  unsigned short* lBc[4];
#pragma unroll
  for (int c = 0; c < 4; c++) {
    const int s = c * 256 + tid;
    const int r = s & 127, kb = s >> 7;  // kb 0..7 (k-chunk of 8)
    gAc[c] = A + (size_t)(bm * 128 + r) * K_ + kb * 8;
    gBc[c] = Bt + (size_t)(bn * 128 + r) * K_ + kb * 8;
    lAc[c] = lA + (size_t)(c * 256 + wid * 64) * 8;
    lBc[c] = lB + (size_t)(c * 256 + wid * 64) * 8;
  }

  f32x4 acc[4][4] = {};
  const int kg = lane >> 4, lr = lane & 15;

  for (int kt = 0; kt < K; kt += 64) {
#pragma unroll
    for (int c = 0; c < 4; c++) {
      gld16(lAc[c], gAc[c] + kt);
      gld16(lBc[c], gBc[c] + kt);
    }
    __syncthreads();
#pragma unroll
    for (int ks = 0; ks < 2; ks++) {
      const int kgi = ks * 4 + kg;
      short8 af[4], bfr[4];
#pragma unroll
      for (int fm = 0; fm < 4; fm++)
        af[fm] = *(const short8*)&lA[(size_t)(kgi * 128 + wm * 64 + fm * 16 + lr) * 8];
#pragma unroll
      for (int fn = 0; fn < 4; fn++)
        bfr[fn] = *(const short8*)&lB[(size_t)(kgi * 128 + wn * 64 + fn * 16 + lr) * 8];
#pragma unroll
      for (int fm = 0; fm < 4; fm++)
#pragma unroll
        for (int fn = 0; fn < 4; fn++)
          acc[fm][fn] =
              __builtin_amdgcn_mfma_f32_16x16x32_bf16(af[fm], bfr[fn], acc[fm][fn], 0, 0, 0);
    }
    __syncthreads();
  }

#pragma unroll
  for (int fn = 0; fn < 4; fn++) {
    const int col = bn * 128 + wn * 64 + fn * 16 + lr;
    const float bv = bias ? bias[col] : 0.f;
#pragma unroll
    for (int fm = 0; fm < 4; fm++) {
      const int row0 = bm * 128 + wm * 64 + fm * 16 + kg * 4;
#pragma unroll
      for (int r = 0; r < 4; r++) {
        const int m = row0 + r;
        if (m < Mvalid) {
          const float v = acc[fm][fn][r] + bv;
          if (mode == 0) {
            ((float*)C)[(size_t)m * N + col] = v;
          } else if (mode == 1) {
            const int b = m & 31, t = m >> 5;
            ((float*)C)[(size_t)b * 2016000 + (size_t)t * 32000 + col] = v;
          } else {
            ((unsigned short*)C)[(size_t)m * N + col] = f2bf(v);
          }
        }
      }
    }
  }
}

// ---------------------------------------------------------------------------
// Encoder chain: grid 32 (dir*16 + jtile32), block 128, 128KB dyn LDS.
// Fresh-address h timeline Henc[t][dir][32][512]; plain coalesced h loads,
// coh_st writes, split-phase generation barrier per dir (16 blocks).
// ---------------------------------------------------------------------------
__global__ __launch_bounds__(128, 1) void enc_chain(
    const unsigned short* __restrict__ Whh, const unsigned short* __restrict__ G,
    unsigned short* __restrict__ Henc, unsigned short* __restrict__ seq_out,
    float* __restrict__ c_out, int* bar) {
  extern __shared__ unsigned short lw[];
  const int tid = threadIdx.x, lane = tid & 63, w = tid >> 6;
  const int lr = lane & 15, kg = lane >> 4;
  const int dir = (int)blockIdx.x >> 4, j0 = ((int)blockIdx.x & 15) * 32;
  int* cnt = bar + dir * 32;
  int* flag = cnt + 16;
  const unsigned short* Wd = Whh + (size_t)dir * 2048 * 512;
  for (int it = 0; it < 64; it++) {
    const int idx = (it * 128 + tid) * 16;
    const int r = idx >> 10, o = idx & 1023;
    const unsigned short* src = Wd + (size_t)((r >> 5) * 512 + j0 + (r & 31)) * 512 + (o >> 1);
    *(short8*)((char*)lw + r * 1024 + (o ^ ((r & 7) << 4))) = *(const short8*)src;
  }
  float cc[2][4] = {};
  float gpre[4][2][4];
  auto fetch_g = [&](int t) {
    const int s_idx = dir ? (63 - t) : t;
#pragma unroll
    for (int r = 0; r < 4; r++) {
      const unsigned short* Gr =
          G + (size_t)(s_idx * 32 + (w * 16 + kg * 4 + r)) * 4096 + dir * 2048;
#pragma unroll
      for (int jh = 0; jh < 2; jh++) {
        const int jj = j0 + jh * 16 + lr;
        gpre[r][jh][0] = bf2f(Gr[jj]);
        gpre[r][jh][1] = bf2f(Gr[512 + jj]);
        gpre[r][jh][2] = bf2f(Gr[1024 + jj]);
        gpre[r][jh][3] = bf2f(Gr[1536 + jj]);
      }
    }
  };
  fetch_g(0);
  __syncthreads();
  for (int t = 0; t < 64; t++) {
    const unsigned short* hA =
        Henc + ((size_t)(t * 2 + dir) * 32 + w * 16 + lr) * 512 + kg * 8;
    short8 areg[16];
#pragma unroll
    for (int kc = 0; kc < 16; kc++) areg[kc] = *(const short8*)(hA + kc * 32);
    f32x4 acc[8] = {};
#pragma unroll
    for (int kc = 0; kc < 16; kc++)
#pragma unroll
      for (int nt = 0; nt < 8; nt++) {
        const int rr = nt * 16 + lr;
        short8 bf = *(const short8*)((const char*)lw + rr * 1024 +
                                     ((kc * 64 + kg * 16) ^ ((rr & 7) << 4)));
        acc[nt] = __builtin_amdgcn_mfma_f32_16x16x32_bf16(areg[kc], bf, acc[nt], 0, 0, 0);
      }
    const int s_idx = dir ? (63 - t) : t;
    unsigned long long* HWU =
        (unsigned long long*)Henc + ((size_t)((t + 1) * 2 + dir) * 32) * 128;
#pragma unroll
    for (int r = 0; r < 4; r++) {
      const int b = w * 16 + kg * 4 + r;
#pragma unroll
      for (int jh = 0; jh < 2; jh++) {
        const float gi = gpre[r][jh][0] + acc[jh + 0][r];
        const float gf = gpre[r][jh][1] + acc[jh + 2][r];
        const float gg = gpre[r][jh][2] + acc[jh + 4][r];
        const float go = gpre[r][jh][3] + acc[jh + 6][r];
        const float cn = sig_(gf) * cc[jh][r] + sig_(gi) * tanh_(gg);
        const float hn = sig_(go) * tanh_(cn);
        cc[jh][r] = cn;
        unsigned long long pk = pack4w((unsigned int)f2bf(hn), lane, 1, 2);
        if ((lane & 3) == 0) {
          const int jjb = j0 + jh * 16 + lr;  // lr multiple of 4 here
          coh_st(HWU + b * 128 + (jjb >> 2), pk);
          if (seq_out)
            *(unsigned long long*)&seq_out[(size_t)(s_idx * 32 + b) * 1024 + dir * 512 +
                                           jjb] = pk;
        }
      }
    }
    if (t < 63) {
      __syncthreads();  // drains h stores (vmcnt) before arrive
      block_arrive(cnt, flag, t * 16 + 15, t + 1);
      fetch_g(t + 1);  // overlap G prefetch with barrier wait
      wave_poll(flag, t);
    }
  }
#pragma unroll
  for (int r = 0; r < 4; r++)
#pragma unroll
    for (int jh = 0; jh < 2; jh++)
      c_out[(dir * 32 + (w * 16 + kg * 4 + r)) * 512 + j0 + jh * 16 + lr] = cc[jh][r];
}

// ---------------------------------------------------------------------------
// Fused decoder pipeline: 192 blocks x 128 thr, 128KB dyn LDS.
// iter k: blocks 0..63   cell0 jtile16, step t=k (k<63): read H0ext slice k,
//                        write slice k+1 (gates from G + Whh0 MFMA).
//         blocks 64..191 cell1 jtile8, step t=k-1 (k>=1): read H0ext slice k
//                        and H1ext slice k-1, full K=2048 dot vs Wc1, write
//                        H1ext slice k. One 192-block gen barrier per iter.
// Fresh-address timelines + plain coalesced loads (round-8 mechanism).
// ---------------------------------------------------------------------------
__global__ __launch_bounds__(128, 1) void dec_pipe(
    const unsigned short* __restrict__ Whh0, const unsigned short* __restrict__ Wc1,
    const unsigned short* __restrict__ G, const float* __restrict__ db1,
    const float* __restrict__ c0init, const float* __restrict__ c1init,
    unsigned short* __restrict__ H0ext, unsigned short* __restrict__ H1ext,
    int* bar) {
  extern __shared__ unsigned short lw[];
  const int tid = threadIdx.x, lane = tid & 63, w = tid >> 6;
  const int lr = lane & 15, kg = lane >> 4;
  const int bid = (int)blockIdx.x;
  int* cnt = bar;
  int* flag = bar + 16;

  if (bid < 64) {
    // ================= cell0 =================
    const int j0 = bid * 16, j = j0 + lr;
    for (int it = 0; it < 64; it++) {
      const int idx = (it * 128 + tid) * 16;
      const int r = idx >> 11, o = idx & 2047;
      const unsigned short* src =
          Whh0 + (size_t)((r >> 4) * 1024 + j0 + (r & 15)) * 1024 + (o >> 1);
      *(short8*)((char*)lw + r * 2048 + (o ^ ((r & 7) << 4))) = *(const short8*)src;
    }
    float cc[4];
#pragma unroll
    for (int r = 0; r < 4; r++) cc[r] = c0init[(w * 16 + kg * 4 + r) * 1024 + j];
    float gpre[4][4];
    auto fetch_g = [&](int k) {
#pragma unroll
      for (int r = 0; r < 4; r++) {
        const unsigned short* Gr = G + (size_t)(k * 32 + (w * 16 + kg * 4 + r)) * 4096 + j;
        gpre[r][0] = bf2f(Gr[0]);
        gpre[r][1] = bf2f(Gr[1024]);
        gpre[r][2] = bf2f(Gr[2048]);
        gpre[r][3] = bf2f(Gr[3072]);
      }
    };
    fetch_g(0);
    __syncthreads();
    for (int k = 0; k < 64; k++) {
      if (k < 63) {
        const unsigned short* hA = H0ext + ((size_t)k * 32 + w * 16 + lr) * 1024 + kg * 8;
        short8 areg[32];
#pragma unroll
        for (int kc = 0; kc < 32; kc++) areg[kc] = *(const short8*)(hA + kc * 32);
        f32x4 acc[4] = {};
#pragma unroll
        for (int kc = 0; kc < 32; kc++)
#pragma unroll
          for (int g = 0; g < 4; g++) {
            const int rr = g * 16 + lr;
            short8 bf = *(const short8*)((const char*)lw + rr * 2048 +
                                         ((kc * 64 + kg * 16) ^ ((rr & 7) << 4)));
            acc[g] = __builtin_amdgcn_mfma_f32_16x16x32_bf16(areg[kc], bf, acc[g], 0, 0, 0);
          }
        unsigned long long* HWU = (unsigned long long*)H0ext + ((size_t)(k + 1) * 32) * 256;
#pragma unroll
        for (int r = 0; r < 4; r++) {
          const int b = w * 16 + kg * 4 + r;
          const float gi = gpre[r][0] + acc[0][r];
          const float gf = gpre[r][1] + acc[1][r];
          const float gg = gpre[r][2] + acc[2][r];
          const float go = gpre[r][3] + acc[3][r];
          const float cn = sig_(gf) * cc[r] + sig_(gi) * tanh_(gg);
          const float hn = sig_(go) * tanh_(cn);
          cc[r] = cn;
          unsigned long long pk = pack4w((unsigned int)f2bf(hn), lane, 1, 2);
          if ((lane & 3) == 0)
            coh_st(HWU + b * 256 + ((j0 + lr) >> 2), pk);
        }
      }
      if (k < 63) {
        __syncthreads();  // drain h stores before arrive
        block_arrive(cnt, flag, k * 192 + 191, k + 1);
        if (k < 62) fetch_g(k + 1);  // overlap G prefetch with barrier wait
        wave_poll(flag, k);
      }
    }
  } else {
    // ================= cell1 (K=2048, packed Wc1=[Wih1|Whh1]) =================
    const int j0 = (bid - 64) * 8;
    for (int it = 0; it < 64; it++) {
      const int idx = (it * 128 + tid) * 16;
      const int r = idx >> 12, o = idx & 4095;
      const unsigned short* src =
          Wc1 + (size_t)((r & 3) * 1024 + j0 + (r >> 2)) * 2048 + (o >> 1);
      *(short8*)((char*)lw + r * 4096 + (o ^ ((r & 7) << 4))) = *(const short8*)src;
    }
    float cc[2][4];
    float bb1[2][4];
#pragma unroll
    for (int n = 0; n < 2; n++) {
      const int j = j0 + n * 4 + (lr >> 2);
#pragma unroll
      for (int g = 0; g < 4; g++) bb1[n][g] = db1[g * 1024 + j];
#pragma unroll
      for (int r = 0; r < 4; r++)
        cc[n][r] = c1init[(w * 16 + kg * 4 + r) * 1024 + j];
    }
    __syncthreads();
    for (int k = 0; k < 64; k++) {
      if (k >= 1) {
        const int t = k - 1;
        f32x4 acc[2] = {};
        {  // first half: A = h0new(t) = H0ext slice k
          const unsigned short* hA = H0ext + ((size_t)k * 32 + w * 16 + lr) * 1024 + kg * 8;
          short8 areg[32];
#pragma unroll
          for (int kc = 0; kc < 32; kc++) areg[kc] = *(const short8*)(hA + kc * 32);
#pragma unroll
          for (int kc = 0; kc < 32; kc++)
#pragma unroll
            for (int n = 0; n < 2; n++) {
              const int rr = n * 16 + lr;
              short8 bf = *(const short8*)((const char*)lw + rr * 4096 +
                                           ((kc * 64 + kg * 16) ^ ((rr & 7) << 4)));
              acc[n] = __builtin_amdgcn_mfma_f32_16x16x32_bf16(areg[kc], bf, acc[n], 0, 0, 0);
            }
        }
        {  // second half: A = h1(t-1) = H1ext slice k-1
          const unsigned short* hA =
              H1ext + ((size_t)(k - 1) * 32 + w * 16 + lr) * 1024 + kg * 8;
          short8 areg[32];
#pragma unroll
          for (int kc = 0; kc < 32; kc++) areg[kc] = *(const short8*)(hA + kc * 32);
#pragma unroll
          for (int kc = 32; kc < 64; kc++)
#pragma unroll
            for (int n = 0; n < 2; n++) {
              const int rr = n * 16 + lr;
              short8 bf = *(const short8*)((const char*)lw + rr * 4096 +
                                           ((kc * 64 + kg * 16) ^ ((rr & 7) << 4)));
              acc[n] = __builtin_amdgcn_mfma_f32_16x16x32_bf16(areg[kc - 32], bf, acc[n],
                                                               0, 0, 0);
            }
        }
        unsigned long long* HWU = (unsigned long long*)H1ext + ((size_t)k * 32) * 256;
#pragma unroll
        for (int n = 0; n < 2; n++) {
#pragma unroll
          for (int r = 0; r < 4; r++) {
            const int b = w * 16 + kg * 4 + r;
            // butterfly: 4-lane group (lane&3) holds gates i,f,g,o of same (b,j)
            const float v = acc[n][r];
            const float e1a = __shfl_xor(v, 1);
            const float e0 = (lane & 1) ? e1a : v;
            const float e1 = (lane & 1) ? v : e1a;
            const float f0 = __shfl_xor(e0, 2), f1 = __shfl_xor(e1, 2);
            const float gi = ((lane & 2) ? f0 : e0) + bb1[n][0];
            const float gf = ((lane & 2) ? f1 : e1) + bb1[n][1];
            const float gg = ((lane & 2) ? e0 : f0) + bb1[n][2];
            const float go = ((lane & 2) ? e1 : f1) + bb1[n][3];
            const float cn = sig_(gf) * cc[n][r] + sig_(gi) * tanh_(gg);
            const float hn = sig_(go) * tanh_(cn);
            cc[n][r] = cn;
            unsigned long long pk = pack4w((unsigned int)f2bf(hn), lane, 4, 8);
            if ((lane & 15) == 0)
              coh_st(HWU + b * 256 + ((j0 + n * 4) >> 2), pk);
          }
        }
        (void)t;
      }
      if (k < 63) {
        __syncthreads();
        block_arrive(cnt, flag, k * 192 + 191, k + 1);
        wave_poll(flag, k);
      }
    }
  }
}

// ---------------------------------------------------------------------------
// Setup kernels
// ---------------------------------------------------------------------------
__global__ void cvt_bf16(const float* __restrict__ in, unsigned short* __restrict__ out,
                         long n4) {
  long i = (long)blockIdx.x * blockDim.x + threadIdx.x;
  const long stride = (long)gridDim.x * blockDim.x;
  for (; i < n4; i += stride) {
    f32x4 v = *(const f32x4*)&in[i * 4];
    ushort4 o = {f2bf(v.x), f2bf(v.y), f2bf(v.z), f2bf(v.w)};
    *(ushort4*)&out[i * 4] = o;
  }
}

// Wc[n][k]: k<1024 from Wih1[n][k], else Whh1[n][k-1024]; grid 4096 x 256
__global__ void pack_wc1(const float* __restrict__ Wih1, const float* __restrict__ Whh1,
                         unsigned short* __restrict__ Wc) {
  const int n = blockIdx.x;
  const int c = threadIdx.x * 8;
  const float* src = (c < 1024) ? (Wih1 + (size_t)n * 1024 + c)
                                : (Whh1 + (size_t)n * 1024 + (c - 1024));
  f32x4 v0 = *(const f32x4*)src;
  f32x4 v1 = *(const f32x4*)(src + 4);
  ushort4 o0 = {f2bf(v0.x), f2bf(v0.y), f2bf(v0.z), f2bf(v0.w)};
  ushort4 o1 = {f2bf(v1.x), f2bf(v1.y), f2bf(v1.z), f2bf(v1.w)};
  *(ushort4*)&Wc[(size_t)n * 2048 + c] = o0;
  *(ushort4*)&Wc[(size_t)n * 2048 + c + 4] = o1;
}

__global__ void bias_comb(const float* __restrict__ a, const float* __restrict__ b,
                          float* __restrict__ out, int n) {
  int i = blockIdx.x * blockDim.x + threadIdx.x;
  if (i < n) out[i] = a[i] + b[i];
}

__global__ void embed_src(const int* __restrict__ x, const float* __restrict__ emb,
                          unsigned short* __restrict__ A0) {
  const int row = blockIdx.x;
  const int s = row >> 5, b = row & 31;
  const int tok = x[b * 64 + (63 - s)];
  const int col = threadIdx.x * 4;
  f32x4 v = *(const f32x4*)(emb + (size_t)tok * 1024 + col);
  ushort4 o = {f2bf(v.x), f2bf(v.y), f2bf(v.z), f2bf(v.w)};
  *(ushort4*)&A0[(size_t)row * 1024 + col] = o;
}

__global__ void embed_tgt(const int* __restrict__ y, const float* __restrict__ emb,
                          unsigned short* __restrict__ inp0) {
  const int row = blockIdx.x;
  const int col = threadIdx.x * 4;
  ushort4 o = {0, 0, 0, 0};
  if (row < 2016) {
    const int t = row >> 5, b = row & 31;
    const int tok = y[b * 64 + t];
    f32x4 v = *(const f32x4*)(emb + (size_t)tok * 1024 + col);
    o = ushort4{f2bf(v.x), f2bf(v.y), f2bf(v.z), f2bf(v.w)};
  } else {
    *(ushort4*)&inp0[(size_t)row * 2048 + 1024 + col] = o;
  }
  *(ushort4*)&inp0[(size_t)row * 2048 + col] = o;
}

__global__ void fill_ctx2(const unsigned short* __restrict__ Hl1,
                          unsigned short* __restrict__ inp0) {
  const int row = blockIdx.x;
  const int b = row & 31;
  const int col = threadIdx.x * 4;
  const int dir = col >> 9, jj = col & 511;
  ushort4 v = *(const ushort4*)(Hl1 + ((size_t)dir * 32 + b) * 512 + jj);
  *(ushort4*)&inp0[(size_t)row * 2048 + 1024 + col] = v;
}

// init slice 0 of H0ext/H1ext + c bufs from encoder finals; grid 128 x 256
__global__ void dec_init2(const unsigned short* __restrict__ Hl0,
                          const unsigned short* __restrict__ Hl1,
                          const float* __restrict__ Cl0, const float* __restrict__ Cl1,
                          unsigned short* __restrict__ H0e, unsigned short* __restrict__ H1e,
                          float* __restrict__ c0, float* __restrict__ c1) {
  const int i = blockIdx.x * 256 + threadIdx.x;
  const int b = i >> 10, col = i & 1023;
  const int dir = col >> 9, jj = col & 511;
  const int se = (dir * 32 + b) * 512 + jj;
  const int de = b * 1024 + col;
  H0e[de] = Hl0[se];
  H1e[de] = Hl1[se];
  c0[de] = Cl0[se];
  c1[de] = Cl1[se];
}

// ---------------------------------------------------------------------------
extern "C" void kernel_launch(void* const* d_in, const int* in_sizes, int n_in,
                              void* d_out, int out_size, void* d_ws, size_t ws_size,
                              hipStream_t stream) {
  const int* x = (const int*)d_in[0];
  const int* y = (const int*)d_in[1];
  const float* src_emb = (const float*)d_in[2];
  const float* tgt_emb = (const float*)d_in[3];
  const float* enc_W_ih = (const float*)d_in[4];
  const float* enc_W_hh = (const float*)d_in[5];
  const float* enc_b_ih = (const float*)d_in[6];
  const float* enc_b_hh = (const float*)d_in[7];
  const float* dec_W_ih0 = (const float*)d_in[8];
  const float* dec_W_ih1 = (const float*)d_in[9];
  const float* dec_W_hh = (const float*)d_in[10];
  const float* dec_b_ih = (const float*)d_in[11];
  const float* dec_b_hh = (const float*)d_in[12];
  const float* W_out = (const float*)d_in[13];
  const float* b_out = (const float*)d_in[14];
  float* out = (float*)d_out;

  char* ws = (char*)d_ws;
  size_t off = 0;
  auto alloc = [&](size_t bytes) -> void* {
    void* p = ws + off;
    off += (bytes + 255) & ~(size_t)255;
    return p;
  };
  unsigned short* A0 = (unsigned short*)alloc(2048ull * 1024 * 2);
  unsigned short* seq1 = (unsigned short*)alloc(2048ull * 1024 * 2);
  unsigned short* Wih_bf = (unsigned short*)alloc(2ull * 4096 * 1024 * 2);
  unsigned short* Wih0_bf = (unsigned short*)alloc(4096ull * 2048 * 2);
  unsigned short* Wout_bf = (unsigned short*)alloc(32000ull * 1024 * 2);
  unsigned short* G = (unsigned short*)alloc(2048ull * 4096 * 2);  // bf16 gates (reused)
  unsigned short* inp0 = (unsigned short*)alloc(2048ull * 2048 * 2);
  unsigned short* Whh_enc_bf = (unsigned short*)alloc(2ull * 2 * 2048 * 512 * 2);
  unsigned short* Whh0_bf = (unsigned short*)alloc(4096ull * 1024 * 2);
  unsigned short* Wc1_bf = (unsigned short*)alloc(4096ull * 2048 * 2);
  unsigned short* H0ext = (unsigned short*)alloc(2080ull * 1024 * 2);  // slice0=init
  unsigned short* H1ext = (unsigned short*)alloc(2080ull * 1024 * 2);
  unsigned short* Henc0 = (unsigned short*)alloc(65ull * 2 * 32 * 512 * 2);  // [t][d][b][j]
  unsigned short* Henc1 = (unsigned short*)alloc(65ull * 2 * 32 * 512 * 2);
  float* encbias = (float*)alloc(2ull * 4096 * 4);
  float* decdb = (float*)alloc(2ull * 4096 * 4);
  float* c_l0 = (float*)alloc(2ull * 32 * 512 * 4);
  float* c_l1 = (float*)alloc(2ull * 32 * 512 * 4);
  float* c0buf = (float*)alloc(32ull * 1024 * 4);
  float* c1buf = (float*)alloc(32ull * 1024 * 4);
  int* bar = (int*)alloc(1024 * 4);  // gen-barrier pairs (stride 32 ints)
  if (off > ws_size) return;

  (void)hipFuncSetAttribute((const void*)enc_chain,
                            hipFuncAttributeMaxDynamicSharedMemorySize, 131072);
  (void)hipFuncSetAttribute((const void*)dec_pipe,
                            hipFuncAttributeMaxDynamicSharedMemorySize, 131072);

  // ---- setup (separate dispatches; fusion under enc L0 regressed r10) ----
  cvt_bf16<<<1024, 256, 0, stream>>>(enc_W_ih, Wih_bf, (2ll * 4096 * 1024) / 4);
  cvt_bf16<<<1024, 256, 0, stream>>>(dec_W_ih0, Wih0_bf, (4096ll * 2048) / 4);
  cvt_bf16<<<2048, 256, 0, stream>>>(W_out, Wout_bf, (32000ll * 1024) / 4);
  cvt_bf16<<<1024, 256, 0, stream>>>(enc_W_hh, Whh_enc_bf, (2ll * 2 * 2048 * 512) / 4);
  cvt_bf16<<<1024, 256, 0, stream>>>(dec_W_hh, Whh0_bf, (4096ll * 1024) / 4);
  pack_wc1<<<4096, 256, 0, stream>>>(dec_W_ih1, dec_W_hh + 4096ll * 1024, Wc1_bf);
  bias_comb<<<32, 256, 0, stream>>>(enc_b_ih, enc_b_hh, encbias, 8192);
  bias_comb<<<32, 256, 0, stream>>>(dec_b_ih, dec_b_hh, decdb, 8192);
  embed_src<<<2048, 256, 0, stream>>>(x, src_emb, A0);
  embed_tgt<<<2048, 256, 0, stream>>>(y, tgt_emb, inp0);
  hipMemsetAsync(Henc0, 0, 2ull * 32 * 512 * 2, stream);  // t=0 slice
  hipMemsetAsync(Henc1, 0, 2ull * 32 * 512 * 2, stream);  // t=0 slice
  hipMemsetAsync(bar, 0, 1024 * 4, stream);               // replay-safe barrier reset

  // ---- encoder layer 0 ----
  gemm_bf16<<<dim3(32, 16), 256, 0, stream>>>(A0, Wih_bf, G, encbias, 1024, 4096, 2048, 2);
  enc_chain<<<32, 128, 131072, stream>>>(Whh_enc_bf, G, Henc0, seq1, c_l0, bar + 0);
  // ---- encoder layer 1 ----
  gemm_bf16<<<dim3(32, 16), 256, 0, stream>>>(seq1, Wih_bf + 4096ull * 1024, G,
                                              encbias + 4096, 1024, 4096, 2048, 2);
  enc_chain<<<32, 128, 131072, stream>>>(Whh_enc_bf + 2ull * 2048 * 512, G, Henc1, nullptr,
                                         c_l1, bar + 128);

  // ---- decoder setup ----
  dec_init2<<<128, 256, 0, stream>>>(Henc0 + 64ull * 2 * 32 * 512,
                                     Henc1 + 64ull * 2 * 32 * 512, c_l0, c_l1,
                                     H0ext, H1ext, c0buf, c1buf);
  fill_ctx2<<<2016, 256, 0, stream>>>(Henc1 + 64ull * 2 * 32 * 512, inp0);
  gemm_bf16<<<dim3(32, 16), 256, 0, stream>>>(inp0, Wih0_bf, G, decdb, 2048, 4096, 2048, 2);

  // ---- fused decoder pipeline (cell0 || cell1, staggered; no G1 GEMM) ----
  dec_pipe<<<192, 128, 131072, stream>>>(Whh0_bf, Wc1_bf, G, decdb + 4096, c0buf, c1buf,
                                         H0ext, H1ext, bar + 256);

  // ---- logits (A = H1ext slices 1..63 = rows 32..2047) ----
  gemm_bf16<<<dim3(250, 16), 256, 0, stream>>>(H1ext + 32ull * 1024, Wout_bf, out, b_out,
                                               1024, 32000, 2016, 1);
}

// Round 12
// 2242.578 us; speedup vs baseline: 1.2671x; 1.1194x over previous
//
#include <hip/hip_runtime.h>

typedef __attribute__((ext_vector_type(8))) short short8;
typedef __attribute__((ext_vector_type(4))) float f32x4;

#define DEVINL __device__ __forceinline__

DEVINL unsigned short f2bf(float f) {
  unsigned int u = __builtin_bit_cast(unsigned int, f);
  unsigned int r = u + 0x7FFFu + ((u >> 16) & 1u);  // RNE
  return (unsigned short)(r >> 16);
}
DEVINL float bf2f(unsigned short u) {
  unsigned int x = ((unsigned int)u) << 16;
  return __builtin_bit_cast(float, x);
}
DEVINL float sig_(float x) { return 1.f / (1.f + __expf(-x)); }
DEVINL float tanh_(float x) { return 2.f / (1.f + __expf(-2.f * x)) - 1.f; }

DEVINL void gld16(void* lds, const void* g) {
  __builtin_amdgcn_global_load_lds(
      (const __attribute__((address_space(1))) unsigned int*)g,
      (__attribute__((address_space(3))) unsigned int*)lds, 16, 0, 0);
}

// ---- coherent 8B store: agent-scope relaxed atomic writes through to the
// coherence point, so cross-XCD readers that L2-miss see fresh data. ----
DEVINL void coh_st(unsigned long long* p, unsigned long long v) {
  __hip_atomic_store(p, v, __ATOMIC_RELAXED, __HIP_MEMORY_SCOPE_AGENT);
}

// pack 4 16-bit lane values (lanes L, L^s0, L^s1, L^(s0|s1)) into one u64
DEVINL unsigned long long pack4w(unsigned int u, int lane, int s0, int s1) {
  unsigned int p1 = (unsigned int)__shfl_xor((int)u, s0);
  unsigned int lo2 = (lane & s0) ? ((p1 & 0xFFFFu) | (u << 16))
                                 : ((u & 0xFFFFu) | (p1 << 16));
  unsigned int p2 = (unsigned int)__shfl_xor((int)lo2, s1);
  unsigned int lo = (lane & s1) ? p2 : lo2;
  unsigned int hi = (lane & s1) ? lo2 : p2;
  return ((unsigned long long)hi << 32) | lo;
}

// ---- contention-free scan barrier: block i stores arr[i]=gen (independent
// addresses, parallel); wave 0 polls all words with coalesced agent loads.
// Generations are monotonic -> no reset race; replay-safe via launch memset.
DEVINL void bar_arrive(int* arr, int idx, int gen) {
  if (threadIdx.x == 0)
    __hip_atomic_store(arr + idx, gen, __ATOMIC_RELAXED, __HIP_MEMORY_SCOPE_AGENT);
}
DEVINL void bar_wait(const int* arr, int nb, int gen) {
  if (threadIdx.x < 64) {
    for (;;) {
      int ok = 1;
      for (int i = (int)threadIdx.x; i < nb; i += 64)
        ok &= (__hip_atomic_load(arr + i, __ATOMIC_RELAXED, __HIP_MEMORY_SCOPE_AGENT) >= gen)
                  ? 1
                  : 0;
      if (__all(ok)) break;
      __builtin_amdgcn_s_sleep(2);
    }
  }
  __builtin_amdgcn_sched_barrier(0);  // keep following loads below the poll
  asm volatile("" ::: "memory");
  __syncthreads();
}

// ---------------------------------------------------------------------------
// bf16 GEMM: C[M,N] = A[M,K] @ Bt[N,K]^T + bias[N].  BK=64, 32 MFMA/iter.
// Grid: (Mtiles, Ntiles) -> consecutive blocks share the B (weight) tile for
// L2 reuse. mode 0: f32 C. mode 1: logits scatter f32. mode 2: bf16 C.
// ---------------------------------------------------------------------------
__global__ __launch_bounds__(256) void gemm_bf16(
    const unsigned short* __restrict__ A, const unsigned short* __restrict__ Bt,
    void* __restrict__ C, const float* __restrict__ bias,
    int K, int N, int Mvalid, int mode) {
  __shared__ unsigned short lA[1024 * 8];
  __shared__ unsigned short lB[1024 * 8];
  const int tid = threadIdx.x;
  const int lane = tid & 63, wid = tid >> 6;
  const int wm = wid >> 1, wn = wid & 1;
  const int bm = blockIdx.x, bn = blockIdx.y;
  const size_t K_ = (size_t)K;

  const unsigned short* gAc[4];
  const unsigned short* gBc[4];
  unsigned short* lAc[4];
  unsigned short* lBc[4];
#pragma unroll
  for (int c = 0; c < 4; c++) {
    const int s = c * 256 + tid;
    const int r = s & 127, kb = s >> 7;  // kb 0..7 (k-chunk of 8)
    gAc[c] = A + (size_t)(bm * 128 + r) * K_ + kb * 8;
    gBc[c] = Bt + (size_t)(bn * 128 + r) * K_ + kb * 8;
    lAc[c] = lA + (size_t)(c * 256 + wid * 64) * 8;
    lBc[c] = lB + (size_t)(c * 256 + wid * 64) * 8;
  }

  f32x4 acc[4][4] = {};
  const int kg = lane >> 4, lr = lane & 15;

  for (int kt = 0; kt < K; kt += 64) {
#pragma unroll
    for (int c = 0; c < 4; c++) {
      gld16(lAc[c], gAc[c] + kt);
      gld16(lBc[c], gBc[c] + kt);
    }
    __syncthreads();
#pragma unroll
    for (int ks = 0; ks < 2; ks++) {
      const int kgi = ks * 4 + kg;
      short8 af[4], bfr[4];
#pragma unroll
      for (int fm = 0; fm < 4; fm++)
        af[fm] = *(const short8*)&lA[(size_t)(kgi * 128 + wm * 64 + fm * 16 + lr) * 8];
#pragma unroll
      for (int fn = 0; fn < 4; fn++)
        bfr[fn] = *(const short8*)&lB[(size_t)(kgi * 128 + wn * 64 + fn * 16 + lr) * 8];
#pragma unroll
      for (int fm = 0; fm < 4; fm++)
#pragma unroll
        for (int fn = 0; fn < 4; fn++)
          acc[fm][fn] =
              __builtin_amdgcn_mfma_f32_16x16x32_bf16(af[fm], bfr[fn], acc[fm][fn], 0, 0, 0);
    }
    __syncthreads();
  }

#pragma unroll
  for (int fn = 0; fn < 4; fn++) {
    const int col = bn * 128 + wn * 64 + fn * 16 + lr;
    const float bv = bias ? bias[col] : 0.f;
#pragma unroll
    for (int fm = 0; fm < 4; fm++) {
      const int row0 = bm * 128 + wm * 64 + fm * 16 + kg * 4;
#pragma unroll
      for (int r = 0; r < 4; r++) {
        const int m = row0 + r;
        if (m < Mvalid) {
          const float v = acc[fm][fn][r] + bv;
          if (mode == 0) {
            ((float*)C)[(size_t)m * N + col] = v;
          } else if (mode == 1) {
            const int b = m & 31, t = m >> 5;
            ((float*)C)[(size_t)b * 2016000 + (size_t)t * 32000 + col] = v;
          } else {
            ((unsigned short*)C)[(size_t)m * N + col] = f2bf(v);
          }
        }
      }
    }
  }
}

// ---------------------------------------------------------------------------
// Encoder chain: grid 32 (dir*16 + jtile32), block 128, 128KB dyn LDS.
// Fresh-address h timeline Henc[t][dir][32][512]; plain coalesced h loads,
// coh_st writes, scan barrier per dir (16 arrival words).
// ---------------------------------------------------------------------------
__global__ __launch_bounds__(128, 1) void enc_chain(
    const unsigned short* __restrict__ Whh, const unsigned short* __restrict__ G,
    unsigned short* __restrict__ Henc, unsigned short* __restrict__ seq_out,
    float* __restrict__ c_out, int* bar) {
  extern __shared__ unsigned short lw[];
  const int tid = threadIdx.x, lane = tid & 63, w = tid >> 6;
  const int lr = lane & 15, kg = lane >> 4;
  const int dir = (int)blockIdx.x >> 4, j0 = ((int)blockIdx.x & 15) * 32;
  int* arr = bar + dir * 64;
  const int aidx = (int)blockIdx.x & 15;
  const unsigned short* Wd = Whh + (size_t)dir * 2048 * 512;
  for (int it = 0; it < 64; it++) {
    const int idx = (it * 128 + tid) * 16;
    const int r = idx >> 10, o = idx & 1023;
    const unsigned short* src = Wd + (size_t)((r >> 5) * 512 + j0 + (r & 31)) * 512 + (o >> 1);
    *(short8*)((char*)lw + r * 1024 + (o ^ ((r & 7) << 4))) = *(const short8*)src;
  }
  float cc[2][4] = {};
  float gpre[4][2][4];
  auto fetch_g = [&](int t) {
    const int s_idx = dir ? (63 - t) : t;
#pragma unroll
    for (int r = 0; r < 4; r++) {
      const unsigned short* Gr =
          G + (size_t)(s_idx * 32 + (w * 16 + kg * 4 + r)) * 4096 + dir * 2048;
#pragma unroll
      for (int jh = 0; jh < 2; jh++) {
        const int jj = j0 + jh * 16 + lr;
        gpre[r][jh][0] = bf2f(Gr[jj]);
        gpre[r][jh][1] = bf2f(Gr[512 + jj]);
        gpre[r][jh][2] = bf2f(Gr[1024 + jj]);
        gpre[r][jh][3] = bf2f(Gr[1536 + jj]);
      }
    }
  };
  fetch_g(0);
  __syncthreads();
  for (int t = 0; t < 64; t++) {
    const unsigned short* hA =
        Henc + ((size_t)(t * 2 + dir) * 32 + w * 16 + lr) * 512 + kg * 8;
    short8 areg[16];
#pragma unroll
    for (int kc = 0; kc < 16; kc++) areg[kc] = *(const short8*)(hA + kc * 32);
    f32x4 acc[8] = {};
#pragma unroll
    for (int kc = 0; kc < 16; kc++)
#pragma unroll
      for (int nt = 0; nt < 8; nt++) {
        const int rr = nt * 16 + lr;
        short8 bf = *(const short8*)((const char*)lw + rr * 1024 +
                                     ((kc * 64 + kg * 16) ^ ((rr & 7) << 4)));
        acc[nt] = __builtin_amdgcn_mfma_f32_16x16x32_bf16(areg[kc], bf, acc[nt], 0, 0, 0);
      }
    const int s_idx = dir ? (63 - t) : t;
    unsigned long long* HWU =
        (unsigned long long*)Henc + ((size_t)((t + 1) * 2 + dir) * 32) * 128;
#pragma unroll
    for (int r = 0; r < 4; r++) {
      const int b = w * 16 + kg * 4 + r;
#pragma unroll
      for (int jh = 0; jh < 2; jh++) {
        const float gi = gpre[r][jh][0] + acc[jh + 0][r];
        const float gf = gpre[r][jh][1] + acc[jh + 2][r];
        const float gg = gpre[r][jh][2] + acc[jh + 4][r];
        const float go = gpre[r][jh][3] + acc[jh + 6][r];
        const float cn = sig_(gf) * cc[jh][r] + sig_(gi) * tanh_(gg);
        const float hn = sig_(go) * tanh_(cn);
        cc[jh][r] = cn;
        unsigned long long pk = pack4w((unsigned int)f2bf(hn), lane, 1, 2);
        if ((lane & 3) == 0) {
          const int jjb = j0 + jh * 16 + lr;  // lr multiple of 4 here
          coh_st(HWU + b * 128 + (jjb >> 2), pk);
          if (seq_out)
            *(unsigned long long*)&seq_out[(size_t)(s_idx * 32 + b) * 1024 + dir * 512 +
                                           jjb] = pk;
        }
      }
    }
    if (t < 63) {
      __syncthreads();  // drains h stores (vmcnt) before arrive
      bar_arrive(arr, aidx, t + 1);
      fetch_g(t + 1);  // overlap G prefetch with barrier wait
      bar_wait(arr, 16, t + 1);
    }
  }
#pragma unroll
  for (int r = 0; r < 4; r++)
#pragma unroll
    for (int jh = 0; jh < 2; jh++)
      c_out[(dir * 32 + (w * 16 + kg * 4 + r)) * 512 + j0 + jh * 16 + lr] = cc[jh][r];
}

// ---------------------------------------------------------------------------
// Fused decoder pipeline: 192 blocks x 128 thr, 128KB dyn LDS.
// iter k: blocks 0..63   cell0 jtile16, step t=k (k<63): read H0ext slice k,
//                        write slice k+1 (gates from G + Whh0 MFMA).
//         blocks 64..191 cell1 jtile8, step t=k-1 (k>=1): read H0ext slice k
//                        and H1ext slice k-1, full K=2048 dot vs Wc1, write
//                        H1ext slice k. One 192-word scan barrier per iter.
// ---------------------------------------------------------------------------
__global__ __launch_bounds__(128, 1) void dec_pipe(
    const unsigned short* __restrict__ Whh0, const unsigned short* __restrict__ Wc1,
    const unsigned short* __restrict__ G, const float* __restrict__ db1,
    const float* __restrict__ c0init, const float* __restrict__ c1init,
    unsigned short* __restrict__ H0ext, unsigned short* __restrict__ H1ext,
    int* bar) {
  extern __shared__ unsigned short lw[];
  const int tid = threadIdx.x, lane = tid & 63, w = tid >> 6;
  const int lr = lane & 15, kg = lane >> 4;
  const int bid = (int)blockIdx.x;

  if (bid < 64) {
    // ================= cell0 =================
    const int j0 = bid * 16, j = j0 + lr;
    for (int it = 0; it < 64; it++) {
      const int idx = (it * 128 + tid) * 16;
      const int r = idx >> 11, o = idx & 2047;
      const unsigned short* src =
          Whh0 + (size_t)((r >> 4) * 1024 + j0 + (r & 15)) * 1024 + (o >> 1);
      *(short8*)((char*)lw + r * 2048 + (o ^ ((r & 7) << 4))) = *(const short8*)src;
    }
    float cc[4];
#pragma unroll
    for (int r = 0; r < 4; r++) cc[r] = c0init[(w * 16 + kg * 4 + r) * 1024 + j];
    float gpre[4][4];
    auto fetch_g = [&](int k) {
#pragma unroll
      for (int r = 0; r < 4; r++) {
        const unsigned short* Gr = G + (size_t)(k * 32 + (w * 16 + kg * 4 + r)) * 4096 + j;
        gpre[r][0] = bf2f(Gr[0]);
        gpre[r][1] = bf2f(Gr[1024]);
        gpre[r][2] = bf2f(Gr[2048]);
        gpre[r][3] = bf2f(Gr[3072]);
      }
    };
    fetch_g(0);
    __syncthreads();
    for (int k = 0; k < 64; k++) {
      if (k < 63) {
        const unsigned short* hA = H0ext + ((size_t)k * 32 + w * 16 + lr) * 1024 + kg * 8;
        short8 areg[32];
#pragma unroll
        for (int kc = 0; kc < 32; kc++) areg[kc] = *(const short8*)(hA + kc * 32);
        f32x4 acc[4] = {};
#pragma unroll
        for (int kc = 0; kc < 32; kc++)
#pragma unroll
          for (int g = 0; g < 4; g++) {
            const int rr = g * 16 + lr;
            short8 bf = *(const short8*)((const char*)lw + rr * 2048 +
                                         ((kc * 64 + kg * 16) ^ ((rr & 7) << 4)));
            acc[g] = __builtin_amdgcn_mfma_f32_16x16x32_bf16(areg[kc], bf, acc[g], 0, 0, 0);
          }
        unsigned long long* HWU = (unsigned long long*)H0ext + ((size_t)(k + 1) * 32) * 256;
#pragma unroll
        for (int r = 0; r < 4; r++) {
          const int b = w * 16 + kg * 4 + r;
          const float gi = gpre[r][0] + acc[0][r];
          const float gf = gpre[r][1] + acc[1][r];
          const float gg = gpre[r][2] + acc[2][r];
          const float go = gpre[r][3] + acc[3][r];
          const float cn = sig_(gf) * cc[r] + sig_(gi) * tanh_(gg);
          const float hn = sig_(go) * tanh_(cn);
          cc[r] = cn;
          unsigned long long pk = pack4w((unsigned int)f2bf(hn), lane, 1, 2);
          if ((lane & 3) == 0)
            coh_st(HWU + b * 256 + ((j0 + lr) >> 2), pk);
        }
      }
      if (k < 63) {
        __syncthreads();  // drain h stores before arrive
        bar_arrive(bar, bid, k + 1);
        if (k < 62) fetch_g(k + 1);  // overlap G prefetch with barrier wait
        bar_wait(bar, 192, k + 1);
      }
    }
  } else {
    // ================= cell1 (K=2048, packed Wc1=[Wih1|Whh1]) =================
    const int j0 = (bid - 64) * 8;
    for (int it = 0; it < 64; it++) {
      const int idx = (it * 128 + tid) * 16;
      const int r = idx >> 12, o = idx & 4095;
      const unsigned short* src =
          Wc1 + (size_t)((r & 3) * 1024 + j0 + (r >> 2)) * 2048 + (o >> 1);
      *(short8*)((char*)lw + r * 4096 + (o ^ ((r & 7) << 4))) = *(const short8*)src;
    }
    float cc[2][4];
    float bb1[2][4];
#pragma unroll
    for (int n = 0; n < 2; n++) {
      const int j = j0 + n * 4 + (lr >> 2);
#pragma unroll
      for (int g = 0; g < 4; g++) bb1[n][g] = db1[g * 1024 + j];
#pragma unroll
      for (int r = 0; r < 4; r++)
        cc[n][r] = c1init[(w * 16 + kg * 4 + r) * 1024 + j];
    }
    __syncthreads();
    for (int k = 0; k < 64; k++) {
      if (k >= 1) {
        f32x4 acc[2] = {};
        {  // first half: A = h0new(t) = H0ext slice k
          const unsigned short* hA = H0ext + ((size_t)k * 32 + w * 16 + lr) * 1024 + kg * 8;
          short8 areg[32];
#pragma unroll
          for (int kc = 0; kc < 32; kc++) areg[kc] = *(const short8*)(hA + kc * 32);
#pragma unroll
          for (int kc = 0; kc < 32; kc++)
#pragma unroll
            for (int n = 0; n < 2; n++) {
              const int rr = n * 16 + lr;
              short8 bf = *(const short8*)((const char*)lw + rr * 4096 +
                                           ((kc * 64 + kg * 16) ^ ((rr & 7) << 4)));
              acc[n] = __builtin_amdgcn_mfma_f32_16x16x32_bf16(areg[kc], bf, acc[n], 0, 0, 0);
            }
        }
        {  // second half: A = h1(t-1) = H1ext slice k-1
          const unsigned short* hA =
              H1ext + ((size_t)(k - 1) * 32 + w * 16 + lr) * 1024 + kg * 8;
          short8 areg[32];
#pragma unroll
          for (int kc = 0; kc < 32; kc++) areg[kc] = *(const short8*)(hA + kc * 32);
#pragma unroll
          for (int kc = 32; kc < 64; kc++)
#pragma unroll
            for (int n = 0; n < 2; n++) {
              const int rr = n * 16 + lr;
              short8 bf = *(const short8*)((const char*)lw + rr * 4096 +
                                           ((kc * 64 + kg * 16) ^ ((rr & 7) << 4)));
              acc[n] = __builtin_amdgcn_mfma_f32_16x16x32_bf16(areg[kc - 32], bf, acc[n],
                                                               0, 0, 0);
            }
        }
        unsigned long long* HWU = (unsigned long long*)H1ext + ((size_t)k * 32) * 256;
#pragma unroll
        for (int n = 0; n < 2; n++) {
#pragma unroll
          for (int r = 0; r < 4; r++) {
            const int b = w * 16 + kg * 4 + r;
            // butterfly: 4-lane group (lane&3) holds gates i,f,g,o of same (b,j)
            const float v = acc[n][r];
            const float e1a = __shfl_xor(v, 1);
            const float e0 = (lane & 1) ? e1a : v;
            const float e1 = (lane & 1) ? v : e1a;
            const float f0 = __shfl_xor(e0, 2), f1 = __shfl_xor(e1, 2);
            const float gi = ((lane & 2) ? f0 : e0) + bb1[n][0];
            const float gf = ((lane & 2) ? f1 : e1) + bb1[n][1];
            const float gg = ((lane & 2) ? e0 : f0) + bb1[n][2];
            const float go = ((lane & 2) ? e1 : f1) + bb1[n][3];
            const float cn = sig_(gf) * cc[n][r] + sig_(gi) * tanh_(gg);
            const float hn = sig_(go) * tanh_(cn);
            cc[n][r] = cn;
            unsigned long long pk = pack4w((unsigned int)f2bf(hn), lane, 4, 8);
            if ((lane & 15) == 0)
              coh_st(HWU + b * 256 + ((j0 + n * 4) >> 2), pk);
          }
        }
      }
      if (k < 63) {
        __syncthreads();
        bar_arrive(bar, bid, k + 1);
        bar_wait(bar, 192, k + 1);
      }
    }
  }
}

// ---------------------------------------------------------------------------
// Setup kernels
// ---------------------------------------------------------------------------
__global__ void cvt_bf16(const float* __restrict__ in, unsigned short* __restrict__ out,
                         long n4) {
  long i = (long)blockIdx.x * blockDim.x + threadIdx.x;
  const long stride = (long)gridDim.x * blockDim.x;
  for (; i < n4; i += stride) {
    f32x4 v = *(const f32x4*)&in[i * 4];
    ushort4 o = {f2bf(v.x), f2bf(v.y), f2bf(v.z), f2bf(v.w)};
    *(ushort4*)&out[i * 4] = o;
  }
}

// Wc[n][k]: k<1024 from Wih1[n][k], else Whh1[n][k-1024]; grid 4096 x 256
__global__ void pack_wc1(const float* __restrict__ Wih1, const float* __restrict__ Whh1,
                         unsigned short* __restrict__ Wc) {
  const int n = blockIdx.x;
  const int c = threadIdx.x * 8;
  const float* src = (c < 1024) ? (Wih1 + (size_t)n * 1024 + c)
                                : (Whh1 + (size_t)n * 1024 + (c - 1024));
  f32x4 v0 = *(const f32x4*)src;
  f32x4 v1 = *(const f32x4*)(src + 4);
  ushort4 o0 = {f2bf(v0.x), f2bf(v0.y), f2bf(v0.z), f2bf(v0.w)};
  ushort4 o1 = {f2bf(v1.x), f2bf(v1.y), f2bf(v1.z), f2bf(v1.w)};
  *(ushort4*)&Wc[(size_t)n * 2048 + c] = o0;
  *(ushort4*)&Wc[(size_t)n * 2048 + c + 4] = o1;
}

__global__ void bias_comb(const float* __restrict__ a, const float* __restrict__ b,
                          float* __restrict__ out, int n) {
  int i = blockIdx.x * blockDim.x + threadIdx.x;
  if (i < n) out[i] = a[i] + b[i];
}

__global__ void embed_src(const int* __restrict__ x, const float* __restrict__ emb,
                          unsigned short* __restrict__ A0) {
  const int row = blockIdx.x;
  const int s = row >> 5, b = row & 31;
  const int tok = x[b * 64 + (63 - s)];
  const int col = threadIdx.x * 4;
  f32x4 v = *(const f32x4*)(emb + (size_t)tok * 1024 + col);
  ushort4 o = {f2bf(v.x), f2bf(v.y), f2bf(v.z), f2bf(v.w)};
  *(ushort4*)&A0[(size_t)row * 1024 + col] = o;
}

__global__ void embed_tgt(const int* __restrict__ y, const float* __restrict__ emb,
                          unsigned short* __restrict__ inp0) {
  const int row = blockIdx.x;
  const int col = threadIdx.x * 4;
  ushort4 o = {0, 0, 0, 0};
  if (row < 2016) {
    const int t = row >> 5, b = row & 31;
    const int tok = y[b * 64 + t];
    f32x4 v = *(const f32x4*)(emb + (size_t)tok * 1024 + col);
    o = ushort4{f2bf(v.x), f2bf(v.y), f2bf(v.z), f2bf(v.w)};
  } else {
    *(ushort4*)&inp0[(size_t)row * 2048 + 1024 + col] = o;
  }
  *(ushort4*)&inp0[(size_t)row * 2048 + col] = o;
}

__global__ void fill_ctx2(const unsigned short* __restrict__ Hl1,
                          unsigned short* __restrict__ inp0) {
  const int row = blockIdx.x;
  const int b = row & 31;
  const int col = threadIdx.x * 4;
  const int dir = col >> 9, jj = col & 511;
  ushort4 v = *(const ushort4*)(Hl1 + ((size_t)dir * 32 + b) * 512 + jj);
  *(ushort4*)&inp0[(size_t)row * 2048 + 1024 + col] = v;
}

// init slice 0 of H0ext/H1ext + c bufs from encoder finals; grid 128 x 256
__global__ void dec_init2(const unsigned short* __restrict__ Hl0,
                          const unsigned short* __restrict__ Hl1,
                          const float* __restrict__ Cl0, const float* __restrict__ Cl1,
                          unsigned short* __restrict__ H0e, unsigned short* __restrict__ H1e,
                          float* __restrict__ c0, float* __restrict__ c1) {
  const int i = blockIdx.x * 256 + threadIdx.x;
  const int b = i >> 10, col = i & 1023;
  const int dir = col >> 9, jj = col & 511;
  const int se = (dir * 32 + b) * 512 + jj;
  const int de = b * 1024 + col;
  H0e[de] = Hl0[se];
  H1e[de] = Hl1[se];
  c0[de] = Cl0[se];
  c1[de] = Cl1[se];
}

// ---------------------------------------------------------------------------
extern "C" void kernel_launch(void* const* d_in, const int* in_sizes, int n_in,
                              void* d_out, int out_size, void* d_ws, size_t ws_size,
                              hipStream_t stream) {
  const int* x = (const int*)d_in[0];
  const int* y = (const int*)d_in[1];
  const float* src_emb = (const float*)d_in[2];
  const float* tgt_emb = (const float*)d_in[3];
  const float* enc_W_ih = (const float*)d_in[4];
  const float* enc_W_hh = (const float*)d_in[5];
  const float* enc_b_ih = (const float*)d_in[6];
  const float* enc_b_hh = (const float*)d_in[7];
  const float* dec_W_ih0 = (const float*)d_in[8];
  const float* dec_W_ih1 = (const float*)d_in[9];
  const float* dec_W_hh = (const float*)d_in[10];
  const float* dec_b_ih = (const float*)d_in[11];
  const float* dec_b_hh = (const float*)d_in[12];
  const float* W_out = (const float*)d_in[13];
  const float* b_out = (const float*)d_in[14];
  float* out = (float*)d_out;

  char* ws = (char*)d_ws;
  size_t off = 0;
  auto alloc = [&](size_t bytes) -> void* {
    void* p = ws + off;
    off += (bytes + 255) & ~(size_t)255;
    return p;
  };
  unsigned short* A0 = (unsigned short*)alloc(2048ull * 1024 * 2);
  unsigned short* seq1 = (unsigned short*)alloc(2048ull * 1024 * 2);
  unsigned short* Wih_bf = (unsigned short*)alloc(2ull * 4096 * 1024 * 2);
  unsigned short* Wih0_bf = (unsigned short*)alloc(4096ull * 2048 * 2);
  unsigned short* Wout_bf = (unsigned short*)alloc(32000ull * 1024 * 2);
  unsigned short* G = (unsigned short*)alloc(2048ull * 4096 * 2);  // bf16 gates (reused)
  unsigned short* inp0 = (unsigned short*)alloc(2048ull * 2048 * 2);
  unsigned short* Whh_enc_bf = (unsigned short*)alloc(2ull * 2 * 2048 * 512 * 2);
  unsigned short* Whh0_bf = (unsigned short*)alloc(4096ull * 1024 * 2);
  unsigned short* Wc1_bf = (unsigned short*)alloc(4096ull * 2048 * 2);
  unsigned short* H0ext = (unsigned short*)alloc(2080ull * 1024 * 2);  // slice0=init
  unsigned short* H1ext = (unsigned short*)alloc(2080ull * 1024 * 2);
  unsigned short* Henc0 = (unsigned short*)alloc(65ull * 2 * 32 * 512 * 2);  // [t][d][b][j]
  unsigned short* Henc1 = (unsigned short*)alloc(65ull * 2 * 32 * 512 * 2);
  float* encbias = (float*)alloc(2ull * 4096 * 4);
  float* decdb = (float*)alloc(2ull * 4096 * 4);
  float* c_l0 = (float*)alloc(2ull * 32 * 512 * 4);
  float* c_l1 = (float*)alloc(2ull * 32 * 512 * 4);
  float* c0buf = (float*)alloc(32ull * 1024 * 4);
  float* c1buf = (float*)alloc(32ull * 1024 * 4);
  int* bar = (int*)alloc(512 * 4);  // arrival-word regions
  if (off > ws_size) return;

  (void)hipFuncSetAttribute((const void*)enc_chain,
                            hipFuncAttributeMaxDynamicSharedMemorySize, 131072);
  (void)hipFuncSetAttribute((const void*)dec_pipe,
                            hipFuncAttributeMaxDynamicSharedMemorySize, 131072);

  // ---- setup ----
  cvt_bf16<<<1024, 256, 0, stream>>>(enc_W_ih, Wih_bf, (2ll * 4096 * 1024) / 4);
  cvt_bf16<<<1024, 256, 0, stream>>>(dec_W_ih0, Wih0_bf, (4096ll * 2048) / 4);
  cvt_bf16<<<2048, 256, 0, stream>>>(W_out, Wout_bf, (32000ll * 1024) / 4);
  cvt_bf16<<<1024, 256, 0, stream>>>(enc_W_hh, Whh_enc_bf, (2ll * 2 * 2048 * 512) / 4);
  cvt_bf16<<<1024, 256, 0, stream>>>(dec_W_hh, Whh0_bf, (4096ll * 1024) / 4);
  pack_wc1<<<4096, 256, 0, stream>>>(dec_W_ih1, dec_W_hh + 4096ll * 1024, Wc1_bf);
  bias_comb<<<32, 256, 0, stream>>>(enc_b_ih, enc_b_hh, encbias, 8192);
  bias_comb<<<32, 256, 0, stream>>>(dec_b_ih, dec_b_hh, decdb, 8192);
  embed_src<<<2048, 256, 0, stream>>>(x, src_emb, A0);
  embed_tgt<<<2048, 256, 0, stream>>>(y, tgt_emb, inp0);
  hipMemsetAsync(Henc0, 0, 2ull * 32 * 512 * 2, stream);  // t=0 slice
  hipMemsetAsync(Henc1, 0, 2ull * 32 * 512 * 2, stream);  // t=0 slice
  hipMemsetAsync(bar, 0, 512 * 4, stream);                // replay-safe barrier reset

  // ---- encoder layer 0 ----
  gemm_bf16<<<dim3(16, 32), 256, 0, stream>>>(A0, Wih_bf, G, encbias, 1024, 4096, 2048, 2);
  enc_chain<<<32, 128, 131072, stream>>>(Whh_enc_bf, G, Henc0, seq1, c_l0, bar + 0);
  // ---- encoder layer 1 ----
  gemm_bf16<<<dim3(16, 32), 256, 0, stream>>>(seq1, Wih_bf + 4096ull * 1024, G,
                                              encbias + 4096, 1024, 4096, 2048, 2);
  enc_chain<<<32, 128, 131072, stream>>>(Whh_enc_bf + 2ull * 2048 * 512, G, Henc1, nullptr,
                                         c_l1, bar + 128);

  // ---- decoder setup ----
  dec_init2<<<128, 256, 0, stream>>>(Henc0 + 64ull * 2 * 32 * 512,
                                     Henc1 + 64ull * 2 * 32 * 512, c_l0, c_l1,
                                     H0ext, H1ext, c0buf, c1buf);
  fill_ctx2<<<2016, 256, 0, stream>>>(Henc1 + 64ull * 2 * 32 * 512, inp0);
  gemm_bf16<<<dim3(16, 32), 256, 0, stream>>>(inp0, Wih0_bf, G, decdb, 2048, 4096, 2048, 2);

  // ---- fused decoder pipeline (cell0 || cell1, staggered; no G1 GEMM) ----
  dec_pipe<<<192, 128, 131072, stream>>>(Whh0_bf, Wc1_bf, G, decdb + 4096, c0buf, c1buf,
                                         H0ext, H1ext, bar + 256);

  // ---- logits (A = H1ext slices 1..63 = rows 32..2047) ----
  gemm_bf16<<<dim3(16, 250), 256, 0, stream>>>(H1ext + 32ull * 1024, Wout_bf, out, b_out,
                                               1024, 32000, 2016, 1);
}